// Round 15
// baseline (231.908 us; speedup 1.0000x reference)
//
#include <hip/hip_runtime.h>
#include <stdint.h>

// ---------------------------------------------------------------------------
// FlatLinear: y = x @ W^T + bias, W = centroids[labels] (4096x4096, K=256 cb)
// M=8192, N=4096, K=4096.
// R15: int8 GEMM with a SMALLER accumulator to buy a 3rd block/CU.
// 128x128 tile, BK=64 bytes, 512 thr = 8 waves (4M x 2N) of 32x64 out
// (acc = 2x4 i32x4 = 32 AGPR; unified regs ~77 <= 85 budget at (512,6)).
// LDS 32 KB/block -> 3 blocks/CU = 24 waves/CU (1.5x R14's TLP), 3
// independent barrier groups hide the per-step drain. Same verified swizzle
// (0 conflicts), same 2-phase vmcnt(0)+barrier schedule, same i8 numerics
// (absmax 4.5 measured). If VGPR collapses (spill, R10-style) -> revert R14.
// ---------------------------------------------------------------------------

typedef __attribute__((ext_vector_type(4))) int    i32x4;
typedef __attribute__((ext_vector_type(4))) float  fvec4;

#define K_DIM 4096
#define N_DIM 4096
#define NSTEP (K_DIM / 64)   // 64 K-steps of 64 int8

__device__ __forceinline__ void async16(const void* g, void* l) {
  __builtin_amdgcn_global_load_lds(
      (const __attribute__((address_space(1))) void*)g,
      (__attribute__((address_space(3))) void*)l, 16, 0, 0);
}

// ---------------- quant W: labels -> int8 via codebook, per-tensor scale ----
__global__ __launch_bounds__(256) void quant_w(const int* __restrict__ labels,
                                               const float* __restrict__ cent,
                                               char* __restrict__ wq,
                                               float* __restrict__ swp, int n) {
  __shared__ float red[256];
  __shared__ char cb[256];
  const int t = threadIdx.x;
  const float c = cent[t];
  red[t] = fabsf(c);
  __syncthreads();
  for (int s = 128; s > 0; s >>= 1) {
    if (t < s) red[t] = fmaxf(red[t], red[t + s]);
    __syncthreads();
  }
  const float m = fmaxf(red[0], 1e-20f);
  cb[t] = (char)(int)rintf(c * (127.f / m));
  if (blockIdx.x == 0 && t == 0) *swp = m / 127.f;
  __syncthreads();
  const int stride = gridDim.x * 256 * 16;
  for (int i = ((int)blockIdx.x * 256 + t) * 16; i < n; i += stride) {
    int out[4];
#pragma unroll
    for (int j = 0; j < 4; ++j) {
      i32x4 l = *(const i32x4*)(labels + i + j * 4);
      out[j] = (cb[l[0]] & 255) | ((cb[l[1]] & 255) << 8) |
               ((cb[l[2]] & 255) << 16) | ((cb[l[3]] & 255) << 24);
    }
    *(i32x4*)(wq + i) = *(i32x4*)out;
  }
}

// ---------------- quant x: per-row max -> int8 + per-row scale --------------
__global__ __launch_bounds__(256) void quant_x(const float* __restrict__ x,
                                               char* __restrict__ xq,
                                               float* __restrict__ sx) {
  __shared__ float red[256];
  const int row = blockIdx.x;
  const float* xr = x + (size_t)row * K_DIM;
  const int t = threadIdx.x;
  fvec4 v[4];
  float mx = 0.f;
#pragma unroll
  for (int j = 0; j < 4; ++j) {
    v[j] = *(const fvec4*)(xr + t * 16 + j * 4);
#pragma unroll
    for (int e = 0; e < 4; ++e) mx = fmaxf(mx, fabsf(v[j][e]));
  }
  red[t] = mx;
  __syncthreads();
  for (int s = 128; s > 0; s >>= 1) {
    if (t < s) red[t] = fmaxf(red[t], red[t + s]);
    __syncthreads();
  }
  const float m = fmaxf(red[0], 1e-20f);
  const float inv = 127.f / m;
  if (t == 0) sx[row] = m / 127.f;
  int out[4];
#pragma unroll
  for (int j = 0; j < 4; ++j) {
    const int q0 = (int)rintf(v[j][0] * inv), q1 = (int)rintf(v[j][1] * inv);
    const int q2 = (int)rintf(v[j][2] * inv), q3 = (int)rintf(v[j][3] * inv);
    out[j] = (q0 & 255) | ((q1 & 255) << 8) | ((q2 & 255) << 16) |
             ((q3 & 255) << 24);
  }
  *(i32x4*)(xq + (size_t)row * K_DIM + t * 16) = *(i32x4*)out;
}

// --------------------------- 128x128-tile int8 GEMM -------------------------
// C[M][N] = sw*sx[m] * (Aq[M][K] . Bq[N][K]^T) + bias.
// Tile 128x128, BK=64 bytes, 512 threads = 8 waves (4M x 2N), wave out 32x64
// (2x4 frags of i32_16x16x64_i8, acc = 32 regs).
// LDS per buffer: A 128x64B (8 KB) + B 128x64B (8 KB), x2 = 32 KB.
// Staging: 2 async16/thread (1 A unit + 1 B unit), wave-uniform dests;
// source 16B-unit pre-swizzled ^((row>>1)&3); reads use the same XOR
// (measured 0 conflicts). Per step: frags, 8 MFMA, vmcnt(0), s_barrier.
// 3 blocks/CU (96 KB LDS, 24 waves/CU) desync hides the drain.
__global__ __launch_bounds__(512, 6) void gemm2(const char* __restrict__ A,
                                                const char* __restrict__ B,
                                                const float* __restrict__ bias,
                                                const float* __restrict__ sxp,
                                                const float* __restrict__ swp,
                                                float* __restrict__ C) {
  __shared__ __align__(16) char As[2][8192];  // [buf][128 rows x 64 B]
  __shared__ __align__(16) char Bs[2][8192];  // [buf][128 rows x 64 B]

  const int tid  = threadIdx.x;
  const int wid  = tid >> 6;
  const int lane = tid & 63;
  const int wm = wid >> 1, wn = wid & 1;
  const int l15 = lane & 15;

  // bijective XCD-aware swizzle (m204)
  const int nwg = gridDim.x, bid = blockIdx.x;
  const int q = nwg >> 3, r = nwg & 7;
  const int xcd = bid & 7, sub = bid >> 3;
  const int swz = (xcd < r ? xcd * (q + 1) : r * (q + 1) + (xcd - r) * q) + sub;
  const int gn = N_DIM / 128;          // 32
  const int bm = swz / gn, bn = swz % gn;

  // ---- staging: thread tid loads 16B-unit tid of A (rows 0..127) and unit
  // tid of B. row = tid>>2; source byte-unit pre-swizzled by ((row>>1)&3)<<4.
  const int srow = tid >> 2;
  const int seu  = ((tid & 3) * 16) ^ (((srow >> 1) & 3) << 4);
  const char* gA = A + (size_t)(bm * 128 + srow) * K_DIM + seu;
  const char* gB = B + (size_t)(bn * 128 + srow) * K_DIM + seu;
  const int wbase = wid * 1024;  // wave-uniform LDS byte base (64 lanes x 16B)

  // ---- fragment read offsets (read-side XOR matches store swizzle):
  //   16B-unit = (lane>>4) ^ ((row>>1)&3), row = <mult of 16> + l15
  const int esw  = ((lane >> 4) * 16) ^ (((l15 >> 1) & 3) << 4);
  const int aOff = (wm * 32 + l15) * 64 + esw;
  const int bOff = (wn * 64 + l15) * 64 + esw;

  i32x4 acc[2][4];
#pragma unroll
  for (int i = 0; i < 2; ++i)
#pragma unroll
    for (int j = 0; j < 4; ++j) acc[i][j] = (i32x4){0, 0, 0, 0};

  i32x4 af[2], bfr[4];

#define STAGE_(b, kt)                    \
  do {                                   \
    async16(gA + (kt), &As[b][wbase]);   \
    async16(gB + (kt), &Bs[b][wbase]);   \
  } while (0)
#define LDFRAG_(b)                                                   \
  do {                                                               \
    _Pragma("unroll") for (int m_ = 0; m_ < 2; ++m_)                 \
        af[m_] = *(const i32x4*)&As[b][aOff + m_ * 1024];            \
    _Pragma("unroll") for (int n_ = 0; n_ < 4; ++n_)                 \
        bfr[n_] = *(const i32x4*)&Bs[b][bOff + n_ * 1024];           \
  } while (0)
#define MM_()                                                        \
  do {                                                               \
    _Pragma("unroll") for (int m_ = 0; m_ < 2; ++m_)                 \
        _Pragma("unroll") for (int n_ = 0; n_ < 4; ++n_)             \
            acc[m_][n_] = __builtin_amdgcn_mfma_i32_16x16x64_i8(     \
                af[m_], bfr[n_], acc[m_][n_], 0, 0, 0);              \
  } while (0)
#define VMW0 asm volatile("s_waitcnt vmcnt(0)" ::: "memory")
#define BAR  __builtin_amdgcn_s_barrier()

  // prologue: stage step 0 into buf 0
  STAGE_(0, 0);
  VMW0;
  BAR;

  // 63 pipelined steps: 31 x (buf0, buf1) + 1 x buf0; tail reads buf1.
  for (int t = 0; t < NSTEP - 2; t += 2) {
    STAGE_(1, (t + 1) * 64);
    LDFRAG_(0); MM_();
    VMW0; BAR;
    STAGE_(0, (t + 2) * 64);
    LDFRAG_(1); MM_();
    VMW0; BAR;
  }
  STAGE_(1, (NSTEP - 1) * 64);
  LDFRAG_(0); MM_();
  VMW0; BAR;
  LDFRAG_(1); MM_();

#undef STAGE_
#undef LDFRAG_
#undef MM_
#undef VMW0
#undef BAR

  // C write: C/D layout col = lane&15, row = (lane>>4)*4 + reg (shape-
  // determined, dtype-independent). y = sw*sx[row]*acc + bias[col].
  const float sw = *swp;
  float bb[4];
#pragma unroll
  for (int n = 0; n < 4; ++n) bb[n] = bias[bn * 128 + wn * 64 + n * 16 + l15];

  float* Cp = C + (size_t)(bm * 128 + wm * 32) * N_DIM + bn * 128 + wn * 64;
  const int rbase = (lane >> 4) * 4;
#pragma unroll
  for (int mi = 0; mi < 2; ++mi)
#pragma unroll
    for (int rr = 0; rr < 4; ++rr) {
      const int grow = bm * 128 + wm * 32 + mi * 16 + rbase + rr;
      const float s = sxp[grow] * sw;
      float* cr = Cp + (size_t)(mi * 16 + rbase + rr) * N_DIM;
#pragma unroll
      for (int n = 0; n < 4; ++n)
        cr[n * 16 + l15] = (float)acc[mi][n][rr] * s + bb[n];
    }
}

// --------------------------- naive fallback (ws too small) ------------------
__global__ void naive_kernel(const float* __restrict__ x,
                             const float* __restrict__ cent,
                             const int* __restrict__ labels,
                             const float* __restrict__ bias,
                             float* __restrict__ out, int M) {
  __shared__ float cb[256];
  if (threadIdx.x < 256) cb[threadIdx.x] = cent[threadIdx.x];
  __syncthreads();
  long o = (long)blockIdx.x * blockDim.x + threadIdx.x;
  if (o >= (long)M * N_DIM) return;
  int n = (int)(o % N_DIM);
  long m = o / N_DIM;
  const float* xr = x + m * K_DIM;
  const int* lr = labels + (long)n * K_DIM;
  float s = 0.f;
  for (int k = 0; k < K_DIM; ++k) s += xr[k] * cb[lr[k]];
  out[o] = s + bias[n];
}

// ---------------------------------------------------------------------------
extern "C" void kernel_launch(void* const* d_in, const int* in_sizes, int n_in,
                              void* d_out, int out_size, void* d_ws, size_t ws_size,
                              hipStream_t stream) {
  const float* x      = (const float*)d_in[0];
  const float* cent   = (const float*)d_in[1];
  const int*   labels = (const int*)d_in[2];
  const float* bias   = (const float*)d_in[3];
  float* out = (float*)d_out;

  const int xN = in_sizes[0];      // M*K
  const int M  = xN / K_DIM;       // 8192
  const int wN = in_sizes[2];      // N*K

  const size_t need = (size_t)wN + (size_t)xN + (size_t)M * 4 + 64;  // ~48 MB
  if (ws_size < need || (M % 128) != 0) {
    long total = (long)M * N_DIM;
    int blocks = (int)((total + 255) / 256);
    naive_kernel<<<blocks, 256, 0, stream>>>(x, cent, labels, bias, out, M);
    return;
  }

  char*  wq  = (char*)d_ws;                 // [N][K] int8
  char*  xq  = wq + (size_t)wN;             // [M][K] int8
  float* sx  = (float*)(xq + (size_t)xN);   // [M] row scales
  float* swp = sx + M;                      // W scale

  quant_w<<<2048, 256, 0, stream>>>(labels, cent, wq, swp, wN);
  quant_x<<<M, 256, 0, stream>>>(x, xq, sx);

  const int grid = (M / 128) * (N_DIM / 128);  // 2048
  gemm2<<<grid, 512, 0, stream>>>(xq, wq, bias, sx, swp, out);
}

// Round 16
// 198.857 us; speedup vs baseline: 1.1662x; 1.1662x over previous
//
#include <hip/hip_runtime.h>
#include <stdint.h>

// ---------------------------------------------------------------------------
// FlatLinear: y = x @ W^T + bias, W = centroids[labels] (4096x4096, K=256 cb)
// M=8192, N=4096, K=4096.
// R16 = R14 champion, byte-identical revert (best measured: 198.8 us total,
// gemm 155 us = ~45% of i8 MFMA ceiling, absmax 4.5).
// INT8 GEMM: 256x128 tile, BK=64 bytes (mfma_i32_16x16x64_i8, NSTEP=64),
// 8 waves 4x2 of 64x64 out, LDS 48 KB 2-buf, 2 blocks/CU, verified
// conflict-free swizzle, 2-phase vmcnt(0)+barrier schedule.
// Occupancy sweep closed: 8/16/24 waves/CU measured -> 16 optimal (R14).
// ---------------------------------------------------------------------------

typedef __attribute__((ext_vector_type(4))) int    i32x4;
typedef __attribute__((ext_vector_type(4))) float  fvec4;

#define K_DIM 4096
#define N_DIM 4096
#define NSTEP (K_DIM / 64)   // 64 K-steps of 64 int8

__device__ __forceinline__ void async16(const void* g, void* l) {
  __builtin_amdgcn_global_load_lds(
      (const __attribute__((address_space(1))) void*)g,
      (__attribute__((address_space(3))) void*)l, 16, 0, 0);
}

// ---------------- quant W: labels -> int8 via codebook, per-tensor scale ----
__global__ __launch_bounds__(256) void quant_w(const int* __restrict__ labels,
                                               const float* __restrict__ cent,
                                               char* __restrict__ wq,
                                               float* __restrict__ swp, int n) {
  __shared__ float red[256];
  __shared__ char cb[256];
  const int t = threadIdx.x;
  const float c = cent[t];
  red[t] = fabsf(c);
  __syncthreads();
  for (int s = 128; s > 0; s >>= 1) {
    if (t < s) red[t] = fmaxf(red[t], red[t + s]);
    __syncthreads();
  }
  const float m = fmaxf(red[0], 1e-20f);
  cb[t] = (char)(int)rintf(c * (127.f / m));
  if (blockIdx.x == 0 && t == 0) *swp = m / 127.f;
  __syncthreads();
  const int stride = gridDim.x * 256 * 16;
  for (int i = ((int)blockIdx.x * 256 + t) * 16; i < n; i += stride) {
    int out[4];
#pragma unroll
    for (int j = 0; j < 4; ++j) {
      i32x4 l = *(const i32x4*)(labels + i + j * 4);
      out[j] = (cb[l[0]] & 255) | ((cb[l[1]] & 255) << 8) |
               ((cb[l[2]] & 255) << 16) | ((cb[l[3]] & 255) << 24);
    }
    *(i32x4*)(wq + i) = *(i32x4*)out;
  }
}

// ---------------- quant x: per-row max -> int8 + per-row scale --------------
__global__ __launch_bounds__(256) void quant_x(const float* __restrict__ x,
                                               char* __restrict__ xq,
                                               float* __restrict__ sx) {
  __shared__ float red[256];
  const int row = blockIdx.x;
  const float* xr = x + (size_t)row * K_DIM;
  const int t = threadIdx.x;
  fvec4 v[4];
  float mx = 0.f;
#pragma unroll
  for (int j = 0; j < 4; ++j) {
    v[j] = *(const fvec4*)(xr + t * 16 + j * 4);
#pragma unroll
    for (int e = 0; e < 4; ++e) mx = fmaxf(mx, fabsf(v[j][e]));
  }
  red[t] = mx;
  __syncthreads();
  for (int s = 128; s > 0; s >>= 1) {
    if (t < s) red[t] = fmaxf(red[t], red[t + s]);
    __syncthreads();
  }
  const float m = fmaxf(red[0], 1e-20f);
  const float inv = 127.f / m;
  if (t == 0) sx[row] = m / 127.f;
  int out[4];
#pragma unroll
  for (int j = 0; j < 4; ++j) {
    const int q0 = (int)rintf(v[j][0] * inv), q1 = (int)rintf(v[j][1] * inv);
    const int q2 = (int)rintf(v[j][2] * inv), q3 = (int)rintf(v[j][3] * inv);
    out[j] = (q0 & 255) | ((q1 & 255) << 8) | ((q2 & 255) << 16) |
             ((q3 & 255) << 24);
  }
  *(i32x4*)(xq + (size_t)row * K_DIM + t * 16) = *(i32x4*)out;
}

// --------------------------- 256x128-tile int8 GEMM -------------------------
// C[M][N] = sw*sx[m] * (Aq[M][K] . Bq[N][K]^T) + bias.
// Tile 256x128, BK=64 bytes, 512 threads = 8 waves (4M x 2N), wave out 64x64.
// LDS per buffer: A 256x64B (16 KB) + B 128x64B (8 KB), x2 = 48 KB.
// Staging 3 async16/thread, wave-uniform dests, source pre-swizzled 16B-unit
// ^= ((row>>1)&3); reads use the same XOR (measured 0 bank conflicts).
// Per step: frags, 16 MFMA (i32_16x16x64_i8), vmcnt(0), s_barrier;
// 2 blocks/CU desync hides the drain.
__global__ __launch_bounds__(512, 4) void gemm2(const char* __restrict__ A,
                                                const char* __restrict__ B,
                                                const float* __restrict__ bias,
                                                const float* __restrict__ sxp,
                                                const float* __restrict__ swp,
                                                float* __restrict__ C) {
  __shared__ __align__(16) char As[2][16384];  // [buf][256 rows x 64 B]
  __shared__ __align__(16) char Bs[2][8192];   // [buf][128 rows x 64 B]

  const int tid  = threadIdx.x;
  const int wid  = tid >> 6;
  const int lane = tid & 63;
  const int wm = wid >> 1, wn = wid & 1;
  const int l15 = lane & 15;

  // bijective XCD-aware swizzle (m204)
  const int nwg = gridDim.x, bid = blockIdx.x;
  const int q = nwg >> 3, r = nwg & 7;
  const int xcd = bid & 7, sub = bid >> 3;
  const int swz = (xcd < r ? xcd * (q + 1) : r * (q + 1) + (xcd - r) * q) + sub;
  const int gn = N_DIM / 128;          // 32
  const int bm = swz / gn, bn = swz % gn;

  // ---- staging: thread tid loads 16B-unit tid of A-low (rows 0..127),
  // A-high (rows 128..255, LDS byte 8192+), B (rows 0..127). row = tid>>2;
  // source byte-unit pre-swizzled by ((row>>1)&3)<<4.
  const int srow = tid >> 2;
  const int seu  = ((tid & 3) * 16) ^ (((srow >> 1) & 3) << 4);
  const char* gA0 = A + (size_t)(bm * 256 + srow) * K_DIM + seu;
  const char* gA1 = gA0 + (size_t)128 * K_DIM;
  const char* gB  = B + (size_t)(bn * 128 + srow) * K_DIM + seu;
  const int wbase = wid * 1024;  // wave-uniform LDS byte base (64 lanes x 16B)

  // ---- fragment read offsets (read-side XOR matches store swizzle):
  //   16B-unit = (lane>>4) ^ ((row>>1)&3), row = <mult of 16> + l15
  const int esw  = ((lane >> 4) * 16) ^ (((l15 >> 1) & 3) << 4);
  const int aOff = (wm * 64 + l15) * 64 + esw;
  const int bOff = (wn * 64 + l15) * 64 + esw;

  i32x4 acc[4][4];
#pragma unroll
  for (int i = 0; i < 4; ++i)
#pragma unroll
    for (int j = 0; j < 4; ++j) acc[i][j] = (i32x4){0, 0, 0, 0};

  i32x4 af[4], bfr[4];

#define STAGE_(b, kt)                               \
  do {                                              \
    async16(gA0 + (kt), &As[b][wbase]);             \
    async16(gA1 + (kt), &As[b][8192 + wbase]);      \
    async16(gB + (kt), &Bs[b][wbase]);              \
  } while (0)
#define LDFRAG_(b)                                                   \
  do {                                                               \
    _Pragma("unroll") for (int m_ = 0; m_ < 4; ++m_)                 \
        af[m_] = *(const i32x4*)&As[b][aOff + m_ * 1024];            \
    _Pragma("unroll") for (int n_ = 0; n_ < 4; ++n_)                 \
        bfr[n_] = *(const i32x4*)&Bs[b][bOff + n_ * 1024];           \
  } while (0)
#define MM_()                                                        \
  do {                                                               \
    _Pragma("unroll") for (int m_ = 0; m_ < 4; ++m_)                 \
        _Pragma("unroll") for (int n_ = 0; n_ < 4; ++n_)             \
            acc[m_][n_] = __builtin_amdgcn_mfma_i32_16x16x64_i8(     \
                af[m_], bfr[n_], acc[m_][n_], 0, 0, 0);              \
  } while (0)
#define VMW0 asm volatile("s_waitcnt vmcnt(0)" ::: "memory")
#define BAR  __builtin_amdgcn_s_barrier()

  // prologue: stage step 0 into buf 0
  STAGE_(0, 0);
  VMW0;
  BAR;

  // 63 pipelined steps: 31 x (buf0, buf1) + 1 x buf0; tail reads buf1.
  for (int t = 0; t < NSTEP - 2; t += 2) {
    STAGE_(1, (t + 1) * 64);
    LDFRAG_(0); MM_();
    VMW0; BAR;
    STAGE_(0, (t + 2) * 64);
    LDFRAG_(1); MM_();
    VMW0; BAR;
  }
  STAGE_(1, (NSTEP - 1) * 64);
  LDFRAG_(0); MM_();
  VMW0; BAR;
  LDFRAG_(1); MM_();

#undef STAGE_
#undef LDFRAG_
#undef MM_
#undef VMW0
#undef BAR

  // C write: C/D layout col = lane&15, row = (lane>>4)*4 + reg (shape-
  // determined, dtype-independent). y = sw*sx[row]*acc + bias[col].
  const float sw = *swp;
  float bb[4];
#pragma unroll
  for (int n = 0; n < 4; ++n) bb[n] = bias[bn * 128 + wn * 64 + n * 16 + l15];

  float* Cp = C + (size_t)(bm * 256 + wm * 64) * N_DIM + bn * 128 + wn * 64;
  const int rbase = (lane >> 4) * 4;
#pragma unroll
  for (int mi = 0; mi < 4; ++mi)
#pragma unroll
    for (int rr = 0; rr < 4; ++rr) {
      const int grow = bm * 256 + wm * 64 + mi * 16 + rbase + rr;
      const float s = sxp[grow] * sw;
      float* cr = Cp + (size_t)(mi * 16 + rbase + rr) * N_DIM;
#pragma unroll
      for (int n = 0; n < 4; ++n)
        cr[n * 16 + l15] = (float)acc[mi][n][rr] * s + bb[n];
    }
}

// --------------------------- naive fallback (ws too small) ------------------
__global__ void naive_kernel(const float* __restrict__ x,
                             const float* __restrict__ cent,
                             const int* __restrict__ labels,
                             const float* __restrict__ bias,
                             float* __restrict__ out, int M) {
  __shared__ float cb[256];
  if (threadIdx.x < 256) cb[threadIdx.x] = cent[threadIdx.x];
  __syncthreads();
  long o = (long)blockIdx.x * blockDim.x + threadIdx.x;
  if (o >= (long)M * N_DIM) return;
  int n = (int)(o % N_DIM);
  long m = o / N_DIM;
  const float* xr = x + m * K_DIM;
  const int* lr = labels + (long)n * K_DIM;
  float s = 0.f;
  for (int k = 0; k < K_DIM; ++k) s += xr[k] * cb[lr[k]];
  out[o] = s + bias[n];
}

// ---------------------------------------------------------------------------
extern "C" void kernel_launch(void* const* d_in, const int* in_sizes, int n_in,
                              void* d_out, int out_size, void* d_ws, size_t ws_size,
                              hipStream_t stream) {
  const float* x      = (const float*)d_in[0];
  const float* cent   = (const float*)d_in[1];
  const int*   labels = (const int*)d_in[2];
  const float* bias   = (const float*)d_in[3];
  float* out = (float*)d_out;

  const int xN = in_sizes[0];      // M*K
  const int M  = xN / K_DIM;       // 8192
  const int wN = in_sizes[2];      // N*K

  const size_t need = (size_t)wN + (size_t)xN + (size_t)M * 4 + 64;  // ~48 MB
  if (ws_size < need || (M % 256) != 0) {
    long total = (long)M * N_DIM;
    int blocks = (int)((total + 255) / 256);
    naive_kernel<<<blocks, 256, 0, stream>>>(x, cent, labels, bias, out, M);
    return;
  }

  char*  wq  = (char*)d_ws;                 // [N][K] int8
  char*  xq  = wq + (size_t)wN;             // [M][K] int8
  float* sx  = (float*)(xq + (size_t)xN);   // [M] row scales
  float* swp = sx + M;                      // W scale

  quant_w<<<2048, 256, 0, stream>>>(labels, cent, wq, swp, wN);
  quant_x<<<M, 256, 0, stream>>>(x, xq, sx);

  const int grid = (M / 256) * (N_DIM / 128);  // 1024
  gemm2<<<grid, 512, 0, stream>>>(xq, wq, bias, sx, swp, out);
}